// Round 10
// baseline (304.375 us; speedup 1.0000x reference)
//
#include <hip/hip_runtime.h>
#include <math.h>

#define KNB 12

// ---------------------------------------------------------------- helpers

__device__ __forceinline__ unsigned umin32(unsigned a, unsigned b) {
    unsigned r; asm("v_min_u32 %0, %1, %2" : "=v"(r) : "v"(a), "v"(b)); return r;
}
__device__ __forceinline__ unsigned umax32(unsigned a, unsigned b) {
    unsigned r; asm("v_max_u32 %0, %1, %2" : "=v"(r) : "v"(a), "v"(b)); return r;
}

// ---------------- f32 no-contract primitives (match CPU netlib rounding)
__device__ __forceinline__ float fm(float a, float b) { return __fmul_rn(a, b); }
__device__ __forceinline__ float fa(float a, float b) { return __fadd_rn(a, b); }
__device__ __forceinline__ float fs(float a, float b) { return __fsub_rn(a, b); }
__device__ __forceinline__ float fsignf(float a, float b) { return (b >= 0.0f) ? fabsf(a) : -fabsf(a); }

__device__ float slapy2_(float x, float y) {
    float xa = fabsf(x), ya = fabsf(y);
    float w = fmaxf(xa, ya), z = fminf(xa, ya);
    if (z == 0.0f) return w;
    float q = z / w;
    return fm(w, __fsqrt_rn(fa(1.0f, fm(q, q))));
}

// LAPACK >=3.10 slartg: c = |f|/d >= 0, r = sign(f)*d
__device__ void slartg_(float f, float g, float& c, float& s, float& r) {
    if (g == 0.0f) { c = 1.0f; s = 0.0f; r = f; }
    else if (f == 0.0f) { c = 0.0f; s = (g >= 0.0f) ? 1.0f : -1.0f; r = fabsf(g); }
    else {
        float d = __fsqrt_rn(fa(fm(f, f), fm(g, g)));
        c = fabsf(f) / d;
        r = (f >= 0.0f) ? d : -d;
        s = g / r;
    }
}

// netlib slaev2 (f32): eigvec of RT1 is (cs1, sn1)
__device__ void slaev2_(float a, float b, float cc,
                        float& rt1, float& rt2, float& cs1, float& sn1) {
    float sm = fa(a, cc), df = fs(a, cc), adf = fabsf(df);
    float tb = fa(b, b), ab = fabsf(tb);
    float acmx, acmn;
    if (fabsf(a) > fabsf(cc)) { acmx = a; acmn = cc; } else { acmx = cc; acmn = a; }
    float rt;
    if (adf > ab)      { float q = ab / adf; rt = fm(adf, __fsqrt_rn(fa(1.0f, fm(q, q)))); }
    else if (adf < ab) { float q = adf / ab; rt = fm(ab,  __fsqrt_rn(fa(1.0f, fm(q, q)))); }
    else               rt = fm(ab, __fsqrt_rn(2.0f));
    int sgn1;
    if (sm < 0.0f) {
        rt1 = fm(0.5f, fs(sm, rt)); sgn1 = -1;
        rt2 = fs(fm(acmx / rt1, acmn), fm(b / rt1, b));
    } else if (sm > 0.0f) {
        rt1 = fm(0.5f, fa(sm, rt)); sgn1 = 1;
        rt2 = fs(fm(acmx / rt1, acmn), fm(b / rt1, b));
    } else { rt1 = fm(0.5f, rt); rt2 = fm(-0.5f, rt); sgn1 = 1; }
    int sgn2; float cs;
    if (df >= 0.0f) { cs = fa(df, rt); sgn2 = 1; } else { cs = fs(df, rt); sgn2 = -1; }
    float acs = fabsf(cs);
    if (acs > ab) {
        float ct = -tb / cs;
        sn1 = 1.0f / __fsqrt_rn(fa(1.0f, fm(ct, ct)));
        cs1 = fm(ct, sn1);
    } else {
        if (ab == 0.0f) { cs1 = 1.0f; sn1 = 0.0f; }
        else {
            float tn = -cs / tb;
            cs1 = 1.0f / __fsqrt_rn(fa(1.0f, fm(tn, tn)));
            sn1 = fm(tn, cs1);
        }
    }
    if (sgn1 == sgn2) { float tn = cs1; cs1 = -sn1; sn1 = tn; }
}

// slasr 'R','V' single rotation, literal netlib expression order
__device__ __forceinline__ void rotcf(float z[4][4], int j1, int j2, float ct, float st) {
    for (int r = 1; r <= 3; ++r) {
        float temp = z[r][j2];
        z[r][j2] = fs(fm(ct, temp), fm(st, z[r][j1]));
        z[r][j1] = fa(fm(st, temp), fm(ct, z[r][j1]));
    }
}

// Faithful f32 port of ssyevd path (ssytd2 'L' -> ssteqr 'I' -> sormtr) for a
// 3x3 symmetric-lower matrix; returns eigvec of the smallest eigenvalue with
// LAPACK's signs.
__device__ void eig3_smallest_f32(float a00, float a10, float a20,
                                  float a11, float a21, float a22,
                                  float& v1o, float& v2o, float& v3o) {
    float d[4], e[3];
    float z[4][4];
    for (int r = 1; r <= 3; ++r)
        for (int c = 1; c <= 3; ++c) z[r][c] = (r == c) ? 1.0f : 0.0f;

    // --- ssytd2 'L' (single Householder on column 1), faithful BLAS op order
    float tau = 0.0f, v3 = 0.0f;
    d[1] = a00;
    if (a20 != 0.0f) {
        float xn = fabsf(a20);                      // snrm2 length-1
        float beta = -fsignf(slapy2_(a10, xn), a10);
        tau = fs(beta, a10) / beta;
        float rinv = 1.0f / fs(a10, beta);          // sscal: recip then mul
        v3 = fm(a20, rinv);
        e[1] = beta;
        // ssymv lower n=2: w = tau * A22 * (1, v3)
        float w1 = fa(fm(tau, a11), fm(tau, fm(a21, v3)));
        float w2 = fa(fm(tau, a21), fm(fm(tau, v3), a22));
        // alpha = -0.5*tau*dot(w, v)
        float dot = fa(w1, fm(w2, v3));
        float al = fm(fm(-0.5f, tau), dot);
        w1 = fa(w1, al);
        w2 = fa(w2, fm(al, v3));
        // ssyr2 lower n=2, alpha=-1, sequential update order
        d[2] = fs(fs(a11, w1), w1);
        e[2] = fs(fs(a21, fm(v3, w1)), w2);
        d[3] = fs(fs(a22, fm(v3, w2)), fm(w2, v3));
    } else {
        e[1] = a10; d[2] = a11; e[2] = a21; d[3] = a22;
    }

    // --- ssteqr 'I' (f32 constants)
    const float eps = 5.9604645e-8f;        // slamch('E') = 2^-24
    const float eps2 = 3.5527137e-15f;      // eps^2
    const float safmin = 1.17549435e-38f;   // slamch('S')
    int jtot = 0; const int nmaxit = 90;
    int l1 = 1;
    while (l1 <= 3) {
        if (l1 > 1) e[l1 - 1] = 0.0f;
        int m;
        for (m = l1; m <= 2; ++m) {
            float tst = fabsf(e[m]);
            if (tst == 0.0f) break;
            if (tst <= fm(fm(__fsqrt_rn(fabsf(d[m])), __fsqrt_rn(fabsf(d[m + 1]))), eps)) {
                e[m] = 0.0f; break;
            }
        }
        int l = l1, lend = m;
        l1 = m + 1;
        if (lend == l) continue;
        if (fabsf(d[lend]) < fabsf(d[l])) { int t = l; l = lend; lend = t; }
        if (lend > l) {
            // QL iteration
            for (;;) {
                int mq = lend;
                if (l != lend) {
                    for (mq = l; mq <= lend - 1; ++mq) {
                        float tst = fm(e[mq], e[mq]);
                        if (tst <= fa(fm(fm(eps2, fabsf(d[mq])), fabsf(d[mq + 1])), safmin)) break;
                    }
                }
                if (mq < lend) e[mq] = 0.0f;
                float p = d[l];
                if (mq == l) { l += 1; if (l <= lend) continue; break; }
                if (mq == l + 1) {
                    float rt1, rt2, cc, ss;
                    slaev2_(d[l], e[l], d[l + 1], rt1, rt2, cc, ss);
                    rotcf(z, l, l + 1, cc, ss);
                    d[l] = rt1; d[l + 1] = rt2; e[l] = 0.0f;
                    l += 2; if (l <= lend) continue; break;
                }
                if (jtot == nmaxit) break;
                jtot++;
                // form shift
                float g = fs(d[l + 1], p) / fm(2.0f, e[l]);
                float r = slapy2_(g, 1.0f);
                g = fa(fs(d[mq], p), e[l] / fa(g, fsignf(r, g)));
                float s_ = 1.0f, c_ = 1.0f; p = 0.0f;
                float wc[3], wsn[3];
                for (int i = mq - 1; i >= l; --i) {
                    float f = fm(s_, e[i]), b = fm(c_, e[i]);
                    slartg_(g, f, c_, s_, r);
                    if (i != mq - 1) e[i + 1] = r;
                    g = fs(d[i + 1], p);
                    r = fa(fm(fs(d[i], g), s_), fm(fm(2.0f, c_), b));
                    p = fm(s_, r);
                    d[i + 1] = fa(g, p);
                    g = fs(fm(c_, r), b);
                    wc[i] = c_; wsn[i] = -s_;      // QL stores -S
                }
                for (int i = mq - 1; i >= l; --i) rotcf(z, i, i + 1, wc[i], wsn[i]);
                d[l] = fs(d[l], p); e[l] = g;
            }
        } else {
            // QR iteration
            for (;;) {
                int mq = lend;
                if (l != lend) {
                    for (mq = l; mq >= lend + 1; --mq) {
                        float tst = fm(e[mq - 1], e[mq - 1]);
                        if (tst <= fa(fm(fm(eps2, fabsf(d[mq])), fabsf(d[mq - 1])), safmin)) break;
                    }
                }
                if (mq > lend) e[mq - 1] = 0.0f;
                float p = d[l];
                if (mq == l) { l -= 1; if (l >= lend) continue; break; }
                if (mq == l - 1) {
                    float rt1, rt2, cc, ss;
                    slaev2_(d[l - 1], e[l - 1], d[l], rt1, rt2, cc, ss);
                    rotcf(z, l - 1, l, cc, ss);
                    d[l - 1] = rt1; d[l] = rt2; e[l - 1] = 0.0f;
                    l -= 2; if (l >= lend) continue; break;
                }
                if (jtot == nmaxit) break;
                jtot++;
                // form shift
                float g = fs(d[l - 1], p) / fm(2.0f, e[l - 1]);
                float r = slapy2_(g, 1.0f);
                g = fa(fs(d[mq], p), e[l - 1] / fa(g, fsignf(r, g)));
                float s_ = 1.0f, c_ = 1.0f; p = 0.0f;
                float wc[3], wsn[3];
                for (int i = mq; i <= l - 1; ++i) {
                    float f = fm(s_, e[i]), b = fm(c_, e[i]);
                    slartg_(g, f, c_, s_, r);
                    if (i != mq) e[i - 1] = r;
                    g = fs(d[i], p);
                    r = fa(fm(fs(d[i + 1], g), s_), fm(fm(2.0f, c_), b));
                    p = fm(s_, r);
                    d[i] = fa(g, p);
                    g = fs(fm(c_, r), b);
                    wc[i] = c_; wsn[i] = s_;      // QR stores +S
                }
                for (int i = mq; i <= l - 1; ++i) rotcf(z, i, i + 1, wc[i], wsn[i]);
                d[l] = fs(d[l], p); e[l - 1] = g;
            }
        }
    }
    // ascending selection sort with column swaps (ssteqr tail)
    for (int ii = 2; ii <= 3; ++ii) {
        int i = ii - 1, kk = i; float p = d[i];
        for (int j = ii; j <= 3; ++j) if (d[j] < p) { kk = j; p = d[j]; }
        if (kk != i) {
            d[kk] = d[i]; d[i] = p;
            for (int r = 1; r <= 3; ++r) { float t = z[r][i]; z[r][i] = z[r][kk]; z[r][kk] = t; }
        }
    }
    // sormtr: Z := H1 * Z (rows 2..3), slarf/sger op order
    if (tau != 0.0f) {
        for (int c = 1; c <= 3; ++c) {
            float ss = fa(z[2][c], fm(v3, z[3][c]));
            float t = fm(tau, ss);
            z[2][c] = fs(z[2][c], t);
            z[3][c] = fs(z[3][c], fm(t, v3));
        }
    }
    v1o = z[1][1]; v2o = z[2][1]; v3o = z[3][1];
}

// ---------------- JAX threefry2x32 (key(42) noise reproduction)
__device__ void threefry2x32_(unsigned k0, unsigned k1, unsigned c0, unsigned c1,
                              unsigned& o0, unsigned& o1) {
    const unsigned rot[8] = {13u, 15u, 26u, 6u, 17u, 29u, 16u, 24u};
    unsigned ks[3] = {k0, k1, k0 ^ k1 ^ 0x1BD11BDAu};
    unsigned x0 = c0 + k0, x1 = c1 + k1;
    for (int blk = 0; blk < 5; ++blk) {
        const unsigned* r = &rot[(blk & 1) * 4];
        for (int i = 0; i < 4; ++i) {
            x0 += x1;
            x1 = (x1 << r[i]) | (x1 >> (32 - r[i]));
            x1 ^= x0;
        }
        x0 += ks[(blk + 1) % 3];
        x1 += ks[(blk + 2) % 3] + (unsigned)(blk + 1);
    }
    o0 = x0; o1 = x1;
}

// noise[j] = (uniform(key(42),(100,3))[j,j] - 0.5) * 1e-8 ; flat idx m = 4*j
__device__ float noise_diag_(int j) {
    unsigned m = (unsigned)(4 * j);
    unsigned o0, o1;
    threefry2x32_(0u, 42u, m, 150u + m, o0, o1);  // m<150 -> first-half output
    unsigned bits = (o0 >> 9) | 0x3f800000u;
    float u = fs(__uint_as_float(bits), 1.0f);    // [0,1)
    return fm(fs(u, 0.5f), 1e-8f);
}

__device__ __forceinline__ float angf(float ax, float ay, float az,
                                      float bx, float by, float bz) {
    float cx = ay * bz - az * by;
    float cy = az * bx - ax * bz;
    float cz = ax * by - ay * bx;
    float cn = sqrtf(cx * cx + cy * cy + cz * cz);
    float d  = ax * bx + ay * by + az * bz;
    return atan2f(cn, d);
}

// ---------------------------------------------------------------- kernels

__global__ void k_prep(const float* __restrict__ pts, float4* __restrict__ pos4, int n) {
    int i = blockIdx.x * blockDim.x + threadIdx.x;
    if (i < n) {
        float x = pts[i * 3], y = pts[i * 3 + 1], z = pts[i * 3 + 2];
        float sq = fa(fa(fm(x, x), fm(y, y)), fm(z, z));
        pos4[i] = make_float4(x, y, z, sq);
    }
}

// Exact brute-force KNN, 12 smallest (d2 asc, idx asc ties). (unchanged R9)
#define KEY_WORST 0xC0001FFFFFFFFFFFull
#define CBUF 128

__global__ __launch_bounds__(256) void k_knn(const float4* __restrict__ pos4,
                                             int* __restrict__ cols, int n) {
    __shared__ unsigned long long sbuf[4][CBUF];
    __shared__ int scnt[4];
    __shared__ unsigned stq[4][4];

    int lane = threadIdx.x & 63;
    int wv = threadIdx.x >> 6;
    int ibase = blockIdx.x * 4;
    int nm1 = n - 1;

    if (threadIdx.x < 4) scnt[threadIdx.x] = 0;

    float4 P[4];
#pragma unroll
    for (int p = 0; p < 4; ++p) {
        int ipp = (ibase + p <= nm1) ? (ibase + p) : nm1;
        P[p] = pos4[ipp];
    }

    int qlen = (n + 3) >> 2;
    int jlo = wv * qlen;
    int jhi = jlo + qlen; if (jhi > n) jhi = n;

    // ---- pass 1: per-lane top-2 raw-bit d2 per point over this quarter
    unsigned b0[4], b1[4];
#pragma unroll
    for (int p = 0; p < 4; ++p) { b0[p] = 0xFFFFFFFFu; b1[p] = 0xFFFFFFFFu; }
    {
        int j0 = jlo + lane; j0 = (j0 <= nm1) ? j0 : nm1;
        float4 Qn = pos4[j0];
        for (int j = jlo + lane; j < jhi; j += 64) {
            float4 Q = Qn;
            int jn = j + 64; jn = (jn <= nm1) ? jn : nm1;
            Qn = pos4[jn];
#pragma unroll
            for (int p = 0; p < 4; ++p) {
                float g = fm(P[p].x, Q.x);
                g = fmaf(P[p].y, Q.y, g);
                g = fmaf(P[p].z, Q.z, g);
                float d2 = fs(fa(P[p].w, Q.w), fm(2.0f, g));
                unsigned u = __float_as_uint(d2);
                unsigned lo = umin32(b0[p], u);
                unsigned hi = umax32(b0[p], u);
                b0[p] = lo;
                b1[p] = umin32(b1[p], hi);
            }
        }
    }

    // ---- quarter-local 13th smallest captured -> stq[p][wv]
#pragma unroll
    for (int p = 0; p < 4; ++p) {
        unsigned h0 = b0[p], h1 = b1[p];
        unsigned T = 0xFFFFFFFFu;
        for (int r = 0; r < KNB + 1; ++r) {
            unsigned mn = h0;
#pragma unroll
            for (int off = 32; off >= 1; off >>= 1) {
                unsigned o = (unsigned)__shfl_xor((int)mn, off, 64);
                mn = umin32(mn, o);
            }
            unsigned long long bl = __ballot(h0 == mn);
            int first = __ffsll(bl) - 1;
            if (lane == first) { h0 = h1; h1 = 0xFFFFFFFFu; }
            T = mn;
        }
        if (lane == 0) stq[p][wv] = T;
    }
    __syncthreads();

    unsigned Tu[4];
#pragma unroll
    for (int p = 0; p < 4; ++p) {
        unsigned t0 = stq[p][0], t1 = stq[p][1], t2 = stq[p][2], t3 = stq[p][3];
        Tu[p] = umax32(umax32(t0, t1), umax32(t2, t3));
    }

    // ---- pass 2: compact candidates with bits <= Tu into shared buffer
    {
        int j0 = jlo + lane; j0 = (j0 <= nm1) ? j0 : nm1;
        float4 Qn = pos4[j0];
        for (int j = jlo + lane; j < jhi; j += 64) {
            float4 Q = Qn;
            int jn = j + 64; jn = (jn <= nm1) ? jn : nm1;
            Qn = pos4[jn];
#pragma unroll
            for (int p = 0; p < 4; ++p) {
                float g = fm(P[p].x, Q.x);
                g = fmaf(P[p].y, Q.y, g);
                g = fmaf(P[p].z, Q.z, g);
                float d2 = fs(fa(P[p].w, Q.w), fm(2.0f, g));
                unsigned u = __float_as_uint(d2);
                bool c = (u <= Tu[p]) && (j != ibase + p);
                unsigned long long bl = __ballot(c);
                if (bl) {
                    int leader = __ffsll(bl) - 1;
                    int base = 0;
                    if (lane == leader)
                        base = atomicAdd(&scnt[p], (int)__popcll(bl));
                    base = __shfl(base, leader, 64);
                    if (c) {
                        int pos = base + (int)__popcll(bl & ((1ull << lane) - 1ull));
                        unsigned us = u ^ (unsigned)(((int)u >> 31) | 0x80000000);
                        unsigned long long kb = (((unsigned long long)us << 13) | (unsigned)j)
                                                | 0xC000000000000000ull;
                        if (pos < CBUF) sbuf[p][pos] = kb;
                    }
                }
            }
        }
    }
    __syncthreads();

    // ---- final: wave wv finalizes point wv (reload from pos4; no runtime
    // indexing of register arrays -- avoids scratch, see R8 post-mortem)
    {
        int io = ibase + wv;
        if (io < n) {
            int cnt = scnt[wv];
            if (cnt > CBUF) {
                float4 Pp = pos4[io];
                unsigned lst[KNB];
#pragma unroll
                for (int k = 0; k < KNB; ++k) lst[k] = 0xFFFFFFFFu;
                for (int j = lane; j < n; j += 64) {
                    float4 Q = pos4[j];
                    float g = fm(Pp.x, Q.x);
                    g = fmaf(Pp.y, Q.y, g);
                    g = fmaf(Pp.z, Q.z, g);
                    float d2 = fs(fa(Pp.w, Q.w), fm(2.0f, g));
                    unsigned u = __float_as_uint(d2);
                    unsigned us = u ^ (unsigned)(((int)u >> 31) | 0x80000000);
                    if (j == io) us = 0xFFFFFFFFu;
#pragma unroll
                    for (int k = 0; k < KNB; ++k) {
                        unsigned lo = umin32(lst[k], us);
                        unsigned hi = umax32(lst[k], us);
                        lst[k] = lo; us = hi;
                    }
                }
                unsigned Ts = 0xFFFFFFFFu;
                for (int r = 0; r < KNB; ++r) {
                    unsigned mn = lst[0];
#pragma unroll
                    for (int off = 32; off >= 1; off >>= 1) {
                        unsigned o = (unsigned)__shfl_xor((int)mn, off, 64);
                        mn = umin32(mn, o);
                    }
                    unsigned long long bl2 = __ballot(lst[0] == mn);
                    int first = __ffsll(bl2) - 1;
                    if (lane == first) {
#pragma unroll
                        for (int k = 0; k < KNB - 1; ++k) lst[k] = lst[k + 1];
                        lst[KNB - 1] = 0xFFFFFFFFu;
                    }
                    Ts = mn;
                }
                if (lane == 0) scnt[wv] = 0;
                __builtin_amdgcn_wave_barrier();
                for (int j = lane; j < n; j += 64) {
                    float4 Q = pos4[j];
                    float g = fm(Pp.x, Q.x);
                    g = fmaf(Pp.y, Q.y, g);
                    g = fmaf(Pp.z, Q.z, g);
                    float d2 = fs(fa(Pp.w, Q.w), fm(2.0f, g));
                    unsigned u = __float_as_uint(d2);
                    unsigned us = u ^ (unsigned)(((int)u >> 31) | 0x80000000);
                    bool c = (us <= Ts) && (j != io);
                    unsigned long long bl2 = __ballot(c);
                    if (bl2) {
                        int leader = __ffsll(bl2) - 1;
                        int base = 0;
                        if (lane == leader)
                            base = atomicAdd(&scnt[wv], (int)__popcll(bl2));
                        base = __shfl(base, leader, 64);
                        if (c) {
                            int pos = base + (int)__popcll(bl2 & ((1ull << lane) - 1ull));
                            unsigned long long kb = (((unsigned long long)us << 13) | (unsigned)j)
                                                    | 0xC000000000000000ull;
                            if (pos < CBUF) sbuf[wv][pos] = kb;
                        }
                    }
                }
                cnt = scnt[wv];
                if (cnt > CBUF) cnt = CBUF;
            }

            double k0 = __longlong_as_double((long long)KEY_WORST);
            double k1 = __longlong_as_double((long long)KEY_WORST);
            if (lane < cnt) k0 = __longlong_as_double((long long)sbuf[wv][lane]);
            if (lane + 64 < cnt) k1 = __longlong_as_double((long long)sbuf[wv][lane + 64]);
            double mykey = __longlong_as_double((long long)KEY_WORST);
            for (int r = 0; r < KNB; ++r) {
                double mx = fmax(k0, k1);
#pragma unroll
                for (int off = 32; off >= 1; off >>= 1)
                    mx = fmax(mx, __shfl_xor(mx, off, 64));
                if (k0 == mx) k0 = __longlong_as_double((long long)KEY_WORST);
                else if (k1 == mx) k1 = __longlong_as_double((long long)KEY_WORST);
                if (lane == r) mykey = mx;
            }
            if (lane < KNB) {
                unsigned long long bits = (unsigned long long)__double_as_longlong(mykey);
                unsigned j = (unsigned)(bits & 0x1FFFu);
                unsigned u = (unsigned)((bits >> 13) & 0xFFFFFFFFull);
                unsigned ob = (u & 0x80000000u) ? (u ^ 0x80000000u) : ~u;
                float d2 = __uint_as_float(ob);
                cols[io * KNB + lane] = (d2 <= 0.25f) ? (int)j : io;
            }
        }
    }
}

__global__ void k_normals(const float4* __restrict__ pos4, const int* __restrict__ cols,
                          float4* __restrict__ nrm4, float* __restrict__ out, int n) {
    int i = blockIdx.x * blockDim.x + threadIdx.x;
    if (i >= n) return;
    float qx[KNB], qy[KNB], qz[KNB];
    for (int k = 0; k < KNB; ++k) {
        float4 q = pos4[cols[i * KNB + k]];
        qx[k] = q.x; qy[k] = q.y; qz[k] = q.z;
    }
    // mean: f32 sequential over k (np.add.reduce, axis not innermost)
    float sx = qx[0], sy = qy[0], sz = qz[0];
    for (int k = 1; k < KNB; ++k) { sx = fa(sx, qx[k]); sy = fa(sy, qy[k]); sz = fa(sz, qz[k]); }
    float mx = sx / 12.0f, my = sy / 12.0f, mz = sz / 12.0f;
    // cov: f32 sequential over k (np.einsum order)
    float c00 = 0, c10 = 0, c20 = 0, c11 = 0, c21 = 0, c22 = 0;
    for (int k = 0; k < KNB; ++k) {
        float dx = fs(qx[k], mx), dy = fs(qy[k], my), dz = fs(qz[k], mz);
        c00 = fa(c00, fm(dx, dx));
        c10 = fa(c10, fm(dy, dx));
        c20 = fa(c20, fm(dz, dx));
        c11 = fa(c11, fm(dy, dy));
        c21 = fa(c21, fm(dz, dy));
        c22 = fa(c22, fm(dz, dz));
    }
    c00 = c00 / 12.0f; c10 = c10 / 12.0f; c20 = c20 / 12.0f;
    c11 = c11 / 12.0f; c21 = c21 / 12.0f; c22 = c22 / 12.0f;
    // + jnp.diag(noise) broadcast over last axis; np eigh reads lower: A[i][j] += v[j]
    float v0 = noise_diag_(0), v1 = noise_diag_(1), v2 = noise_diag_(2);
    float a00 = fa(c00, v0), a10 = fa(c10, v0), a20 = fa(c20, v0);
    float a11 = fa(c11, v1), a21 = fa(c21, v1), a22 = fa(c22, v2);
    float e1, e2, e3;
    eig3_smallest_f32(a00, a10, a20, a11, a21, a22, e1, e2, e3);
    nrm4[i] = make_float4(e1, e2, e3, 0.0f);
    out[i]         = e1;
    out[n + i]     = e2;
    out[2 * n + i] = e3;
}

// ---------------------------------------------------------------- MLP chain
// Weights are read DIRECTLY FROM GLOBAL with wave-uniform addresses -> the
// compiler emits s_load through the scalar/constant cache (SMEM pipe).
// R9's LDS-staged weights made every fmaf a ds_read (~5-8k ds_read/wave,
// ~5.8 cyc each) -- the LDS pipe, shared by 4 SIMDs, was the hidden
// bottleneck. LDS now holds only inter-stage buffers (13.5 KB/block).

struct WPtrs { const float* p[28]; };

template <int NI, int NH, int NO>
__device__ void mlpg(const float* __restrict__ w1, const float* __restrict__ b1,
                     const float* __restrict__ w2, const float* __restrict__ b2,
                     const float* in, float* out) {
#pragma unroll
    for (int o = 0; o < NO; ++o) out[o] = b2[o];
    for (int h = 0; h < NH; ++h) {
        float hh = b1[h];
#pragma unroll
        for (int ii = 0; ii < NI; ++ii) hh = fmaf(in[ii], w1[ii * NH + h], hh);
        hh = fmaxf(hh, 0.0f);
#pragma unroll
        for (int o = 0; o < NO; ++o) out[o] = fmaf(hh, w2[h * NO + o], out[o]);
    }
}

__global__ __launch_bounds__(192) void k_mlp(const float4* __restrict__ pos4,
                                             const int* __restrict__ cols,
                                             const float4* __restrict__ nrm4,
                                             WPtrs wp, float* __restrict__ out, int n) {
    __shared__ float sx[16 * 12 * 16];
    __shared__ float sg[16 * 12];
    __shared__ float smat[16 * 9];
    __shared__ float sfeat[16 * 8];
    __shared__ float slog[16 * 12];
    __shared__ float sred[16 * 2];

    int p = threadIdx.x / 12, k = threadIdx.x - p * 12;
    int nn = blockIdx.x * 16 + p;
    bool act = (nn < n);

    float cx = 0, cy = 0, cz = 0, nrx = 0, nry = 0, nrz = 0;
    float xr[16];

    // stage A: edge features + l1
    if (act) {
        int col = cols[nn * 12 + k];
        float4 P = pos4[nn], Q = pos4[col];
        cx = Q.x - P.x; cy = Q.y - P.y; cz = Q.z - P.z;
        float dist = sqrtf(cx * cx + cy * cy + cz * cz);
        float4 NR = nrm4[nn], NC = nrm4[col];
        nrx = NR.x; nry = NR.y; nrz = NR.z;
        float a1 = angf(nrx, nry, nrz, cx, cy, cz);
        float a2 = angf(NC.x, NC.y, NC.z, cx, cy, cz);
        float a3 = angf(nrx, nry, nrz, NC.x, NC.y, NC.z);
        float in7[7] = {cx, cy, cz, dist, a1, a2, a3};
        mlpg<7, 32, 16>(wp.p[0], wp.p[1], wp.p[2], wp.p[3], in7, xr);
#pragma unroll
        for (int o = 0; o < 16; ++o) sx[(p * 12 + k) * 16 + o] = xr[o];
    }
    __syncthreads();

    // stage B: g1
    if (act && k == 0) {
        float in19[19];
#pragma unroll
        for (int o = 0; o < 16; ++o) {
            float s = 0;
            for (int kk = 0; kk < 12; ++kk) s += sx[(p * 12 + kk) * 16 + o];
            in19[o] = s / 12.0f;
        }
        in19[16] = nrx; in19[17] = nry; in19[18] = nrz;
        float og[8];
        mlpg<19, 32, 8>(wp.p[4], wp.p[5], wp.p[6], wp.p[7], in19, og);
#pragma unroll
        for (int o = 0; o < 8; ++o) sg[p * 12 + o] = og[o];
    }
    __syncthreads();

    // stage C: l2
    if (act) {
        float in24[24];
#pragma unroll
        for (int o = 0; o < 16; ++o) in24[o] = xr[o];
#pragma unroll
        for (int o = 0; o < 8; ++o) in24[16 + o] = sg[p * 12 + o];
        mlpg<24, 32, 16>(wp.p[8], wp.p[9], wp.p[10], wp.p[11], in24, xr);
#pragma unroll
        for (int o = 0; o < 16; ++o) sx[(p * 12 + k) * 16 + o] = xr[o];
    }
    __syncthreads();

    // stage D: g2
    if (act && k == 0) {
        float in16[16];
#pragma unroll
        for (int o = 0; o < 16; ++o) {
            float s = 0;
            for (int kk = 0; kk < 12; ++kk) s += sx[(p * 12 + kk) * 16 + o];
            in16[o] = s / 12.0f;
        }
        float og[8];
        mlpg<16, 32, 8>(wp.p[12], wp.p[13], wp.p[14], wp.p[15], in16, og);
#pragma unroll
        for (int o = 0; o < 8; ++o) sg[p * 12 + o] = og[o];
    }
    __syncthreads();

    // stage E: l3
    if (act) {
        float in24[24];
#pragma unroll
        for (int o = 0; o < 16; ++o) in24[o] = xr[o];
#pragma unroll
        for (int o = 0; o < 8; ++o) in24[16 + o] = sg[p * 12 + o];
        mlpg<24, 32, 16>(wp.p[16], wp.p[17], wp.p[18], wp.p[19], in24, xr);
#pragma unroll
        for (int o = 0; o < 16; ++o) sx[(p * 12 + k) * 16 + o] = xr[o];
    }
    __syncthreads();

    // stage F: g3 + quat -> rot matrix
    if (act && k == 0) {
        float in16[16];
#pragma unroll
        for (int o = 0; o < 16; ++o) {
            float s = 0;
            for (int kk = 0; kk < 12; ++kk) s += sx[(p * 12 + kk) * 16 + o];
            in16[o] = s / 12.0f;
        }
        float og[12];
        mlpg<16, 32, 12>(wp.p[20], wp.p[21], wp.p[22], wp.p[23], in16, og);
        float q0 = og[0], q1 = og[1], q2 = og[2], q3 = og[3];
        float qn = sqrtf(q0 * q0 + q1 * q1 + q2 * q2 + q3 * q3) + 1e-8f;
        q0 /= qn; q1 /= qn; q2 /= qn; q3 /= qn;
        float qw = q0, qx = q1, qy = q2, qz = q3;
        smat[p * 9 + 0] = 1.0f - 2.0f * (qy * qy + qz * qz);
        smat[p * 9 + 1] = 2.0f * (qx * qy - qz * qw);
        smat[p * 9 + 2] = 2.0f * (qx * qz + qy * qw);
        smat[p * 9 + 3] = 2.0f * (qx * qy + qz * qw);
        smat[p * 9 + 4] = 1.0f - 2.0f * (qx * qx + qz * qz);
        smat[p * 9 + 5] = 2.0f * (qy * qz - qx * qw);
        smat[p * 9 + 6] = 2.0f * (qx * qz - qy * qw);
        smat[p * 9 + 7] = 2.0f * (qy * qz + qx * qw);
        smat[p * 9 + 8] = 1.0f - 2.0f * (qx * qx + qy * qy);
#pragma unroll
        for (int o = 0; o < 8; ++o) sfeat[p * 8 + o] = og[4 + o];
    }
    __syncthreads();

    // stage G: l4 logits
    if (act) {
        float r0 = smat[p * 9 + 0] * cx + smat[p * 9 + 1] * cy + smat[p * 9 + 2] * cz;
        float r1 = smat[p * 9 + 3] * cx + smat[p * 9 + 4] * cy + smat[p * 9 + 5] * cz;
        float r2 = smat[p * 9 + 6] * cx + smat[p * 9 + 7] * cy + smat[p * 9 + 8] * cz;
        float in27[27];
#pragma unroll
        for (int o = 0; o < 16; ++o) in27[o] = xr[o];
#pragma unroll
        for (int o = 0; o < 8; ++o) in27[16 + o] = sfeat[p * 8 + o];
        in27[24] = r0; in27[25] = r1; in27[26] = r2;
        float lg[1];
        mlpg<27, 64, 1>(wp.p[24], wp.p[25], wp.p[26], wp.p[27], in27, lg);
        slog[p * 12 + k] = lg[0];
    }
    __syncthreads();

    // stage H: softmax over the 12 edges
    if (act && k == 0) {
        float mx = slog[p * 12];
        for (int kk = 1; kk < 12; ++kk) mx = fmaxf(mx, slog[p * 12 + kk]);
        float se = 0;
        for (int kk = 0; kk < 12; ++kk) se += expf(slog[p * 12 + kk] - mx);
        sred[p * 2] = mx; sred[p * 2 + 1] = se;
    }
    __syncthreads();
    if (act) {
        float v = expf(slog[p * 12 + k] - sred[p * 2]) / sred[p * 2 + 1];
        out[3 * n + k * n + nn] = v;
    }
}

// ---------------------------------------------------------------- launch

extern "C" void kernel_launch(void* const* d_in, const int* in_sizes, int n_in,
                              void* d_out, int out_size, void* d_ws, size_t ws_size,
                              hipStream_t stream) {
    const float* pts = (const float*)d_in[0];
    int n = in_sizes[0] / 3;

    float4* pos4 = (float4*)d_ws;
    int*    cols = (int*)((char*)d_ws + (size_t)n * 16);
    float4* nrm4 = (float4*)((char*)d_ws + (size_t)n * 16 + (size_t)n * KNB * 4);
    float*  out  = (float*)d_out;

    WPtrs wp;
    for (int a = 0; a < 28; ++a) wp.p[a] = (const float*)d_in[a + 1];

    k_prep<<<(n + 255) / 256, 256, 0, stream>>>(pts, pos4, n);
    // 4 points per block; 4 waves split the candidate range (j) in quarters
    k_knn<<<(n + 3) / 4, 256, 0, stream>>>(pos4, cols, n);
    // block=64: spread the divergent serial eig across more CUs
    k_normals<<<(n + 63) / 64, 64, 0, stream>>>(pos4, cols, nrm4, out, n);
    k_mlp<<<(n + 15) / 16, 192, 0, stream>>>(pos4, cols, nrm4, wp, out, n);
}

// Round 11
// 288.887 us; speedup vs baseline: 1.0536x; 1.0536x over previous
//
#include <hip/hip_runtime.h>
#include <math.h>

#define KNB 12

// ---------------------------------------------------------------- helpers

__device__ __forceinline__ unsigned umin32(unsigned a, unsigned b) {
    unsigned r; asm("v_min_u32 %0, %1, %2" : "=v"(r) : "v"(a), "v"(b)); return r;
}
__device__ __forceinline__ unsigned umax32(unsigned a, unsigned b) {
    unsigned r; asm("v_max_u32 %0, %1, %2" : "=v"(r) : "v"(a), "v"(b)); return r;
}

// ---------------- f32 no-contract primitives (match CPU netlib rounding)
__device__ __forceinline__ float fm(float a, float b) { return __fmul_rn(a, b); }
__device__ __forceinline__ float fa(float a, float b) { return __fadd_rn(a, b); }
__device__ __forceinline__ float fs(float a, float b) { return __fsub_rn(a, b); }
__device__ __forceinline__ float fsignf(float a, float b) { return (b >= 0.0f) ? fabsf(a) : -fabsf(a); }

__device__ float slapy2_(float x, float y) {
    float xa = fabsf(x), ya = fabsf(y);
    float w = fmaxf(xa, ya), z = fminf(xa, ya);
    if (z == 0.0f) return w;
    float q = z / w;
    return fm(w, __fsqrt_rn(fa(1.0f, fm(q, q))));
}

// LAPACK >=3.10 slartg: c = |f|/d >= 0, r = sign(f)*d
__device__ void slartg_(float f, float g, float& c, float& s, float& r) {
    if (g == 0.0f) { c = 1.0f; s = 0.0f; r = f; }
    else if (f == 0.0f) { c = 0.0f; s = (g >= 0.0f) ? 1.0f : -1.0f; r = fabsf(g); }
    else {
        float d = __fsqrt_rn(fa(fm(f, f), fm(g, g)));
        c = fabsf(f) / d;
        r = (f >= 0.0f) ? d : -d;
        s = g / r;
    }
}

// netlib slaev2 (f32): eigvec of RT1 is (cs1, sn1)
__device__ void slaev2_(float a, float b, float cc,
                        float& rt1, float& rt2, float& cs1, float& sn1) {
    float sm = fa(a, cc), df = fs(a, cc), adf = fabsf(df);
    float tb = fa(b, b), ab = fabsf(tb);
    float acmx, acmn;
    if (fabsf(a) > fabsf(cc)) { acmx = a; acmn = cc; } else { acmx = cc; acmn = a; }
    float rt;
    if (adf > ab)      { float q = ab / adf; rt = fm(adf, __fsqrt_rn(fa(1.0f, fm(q, q)))); }
    else if (adf < ab) { float q = adf / ab; rt = fm(ab,  __fsqrt_rn(fa(1.0f, fm(q, q)))); }
    else               rt = fm(ab, __fsqrt_rn(2.0f));
    int sgn1;
    if (sm < 0.0f) {
        rt1 = fm(0.5f, fs(sm, rt)); sgn1 = -1;
        rt2 = fs(fm(acmx / rt1, acmn), fm(b / rt1, b));
    } else if (sm > 0.0f) {
        rt1 = fm(0.5f, fa(sm, rt)); sgn1 = 1;
        rt2 = fs(fm(acmx / rt1, acmn), fm(b / rt1, b));
    } else { rt1 = fm(0.5f, rt); rt2 = fm(-0.5f, rt); sgn1 = 1; }
    int sgn2; float cs;
    if (df >= 0.0f) { cs = fa(df, rt); sgn2 = 1; } else { cs = fs(df, rt); sgn2 = -1; }
    float acs = fabsf(cs);
    if (acs > ab) {
        float ct = -tb / cs;
        sn1 = 1.0f / __fsqrt_rn(fa(1.0f, fm(ct, ct)));
        cs1 = fm(ct, sn1);
    } else {
        if (ab == 0.0f) { cs1 = 1.0f; sn1 = 0.0f; }
        else {
            float tn = -cs / tb;
            cs1 = 1.0f / __fsqrt_rn(fa(1.0f, fm(tn, tn)));
            sn1 = fm(tn, cs1);
        }
    }
    if (sgn1 == sgn2) { float tn = cs1; cs1 = -sn1; sn1 = tn; }
}

// ---- per-thread LDS workspace layout (stride 19 floats, odd -> no bank hot)
// Z(r,c): 0..8  (r,c in 1..3) | D(i): 9..11 | E(i): 12..13 | WC: 14..15 | WSN: 16..17
#define Z(r, c)  wk[((r) - 1) * 3 + ((c) - 1)]
#define D(i)     wk[8 + (i)]
#define E(i)     wk[11 + (i)]
#define WC(i)    wk[13 + (i)]
#define WSN(i)   wk[15 + (i)]

// slasr 'R','V' single rotation, literal netlib expression order (LDS Z)
__device__ __forceinline__ void rotcf(float* wk, int j1, int j2, float ct, float st) {
    for (int r = 1; r <= 3; ++r) {
        float temp = Z(r, j2);
        Z(r, j2) = fs(fm(ct, temp), fm(st, Z(r, j1)));
        Z(r, j1) = fa(fm(st, temp), fm(ct, Z(r, j1)));
    }
}

// Faithful f32 port of ssyevd path (ssytd2 'L' -> ssteqr 'I' -> sormtr) for a
// 3x3 symmetric-lower matrix; eigvec of the smallest eigenvalue, LAPACK signs.
// Workspace arrays live in LDS (wk) -- dynamic indexing in scratch cost
// ~300 cyc/access serially (R8 lesson); LDS is ~6 cyc.
__device__ void eig3_smallest_f32(float* wk,
                                  float a00, float a10, float a20,
                                  float a11, float a21, float a22,
                                  float& v1o, float& v2o, float& v3o) {
    for (int r = 1; r <= 3; ++r)
        for (int c = 1; c <= 3; ++c) Z(r, c) = (r == c) ? 1.0f : 0.0f;

    // --- ssytd2 'L' (single Householder on column 1), faithful BLAS op order
    float tau = 0.0f, v3 = 0.0f;
    D(1) = a00;
    if (a20 != 0.0f) {
        float xn = fabsf(a20);                      // snrm2 length-1
        float beta = -fsignf(slapy2_(a10, xn), a10);
        tau = fs(beta, a10) / beta;
        float rinv = 1.0f / fs(a10, beta);          // sscal: recip then mul
        v3 = fm(a20, rinv);
        E(1) = beta;
        // ssymv lower n=2: w = tau * A22 * (1, v3)
        float w1 = fa(fm(tau, a11), fm(tau, fm(a21, v3)));
        float w2 = fa(fm(tau, a21), fm(fm(tau, v3), a22));
        float dot = fa(w1, fm(w2, v3));
        float al = fm(fm(-0.5f, tau), dot);
        w1 = fa(w1, al);
        w2 = fa(w2, fm(al, v3));
        D(2) = fs(fs(a11, w1), w1);
        E(2) = fs(fs(a21, fm(v3, w1)), w2);
        D(3) = fs(fs(a22, fm(v3, w2)), fm(w2, v3));
    } else {
        E(1) = a10; D(2) = a11; E(2) = a21; D(3) = a22;
    }

    // --- ssteqr 'I' (f32 constants)
    const float eps = 5.9604645e-8f;        // slamch('E') = 2^-24
    const float eps2 = 3.5527137e-15f;      // eps^2
    const float safmin = 1.17549435e-38f;   // slamch('S')
    int jtot = 0; const int nmaxit = 90;
    int l1 = 1;
    while (l1 <= 3) {
        if (l1 > 1) E(l1 - 1) = 0.0f;
        int m;
        for (m = l1; m <= 2; ++m) {
            float tst = fabsf(E(m));
            if (tst == 0.0f) break;
            if (tst <= fm(fm(__fsqrt_rn(fabsf(D(m))), __fsqrt_rn(fabsf(D(m + 1)))), eps)) {
                E(m) = 0.0f; break;
            }
        }
        int l = l1, lend = m;
        l1 = m + 1;
        if (lend == l) continue;
        if (fabsf(D(lend)) < fabsf(D(l))) { int t = l; l = lend; lend = t; }
        if (lend > l) {
            // QL iteration
            for (;;) {
                int mq = lend;
                if (l != lend) {
                    for (mq = l; mq <= lend - 1; ++mq) {
                        float tst = fm(E(mq), E(mq));
                        if (tst <= fa(fm(fm(eps2, fabsf(D(mq))), fabsf(D(mq + 1))), safmin)) break;
                    }
                }
                if (mq < lend) E(mq) = 0.0f;
                float p = D(l);
                if (mq == l) { l += 1; if (l <= lend) continue; break; }
                if (mq == l + 1) {
                    float rt1, rt2, cc, ss;
                    slaev2_(D(l), E(l), D(l + 1), rt1, rt2, cc, ss);
                    rotcf(wk, l, l + 1, cc, ss);
                    D(l) = rt1; D(l + 1) = rt2; E(l) = 0.0f;
                    l += 2; if (l <= lend) continue; break;
                }
                if (jtot == nmaxit) break;
                jtot++;
                // form shift
                float g = fs(D(l + 1), p) / fm(2.0f, E(l));
                float r = slapy2_(g, 1.0f);
                g = fa(fs(D(mq), p), E(l) / fa(g, fsignf(r, g)));
                float s_ = 1.0f, c_ = 1.0f; p = 0.0f;
                for (int i = mq - 1; i >= l; --i) {
                    float f = fm(s_, E(i)), b = fm(c_, E(i));
                    slartg_(g, f, c_, s_, r);
                    if (i != mq - 1) E(i + 1) = r;
                    g = fs(D(i + 1), p);
                    r = fa(fm(fs(D(i), g), s_), fm(fm(2.0f, c_), b));
                    p = fm(s_, r);
                    D(i + 1) = fa(g, p);
                    g = fs(fm(c_, r), b);
                    WC(i) = c_; WSN(i) = -s_;      // QL stores -S
                }
                for (int i = mq - 1; i >= l; --i) rotcf(wk, i, i + 1, WC(i), WSN(i));
                D(l) = fs(D(l), p); E(l) = g;
            }
        } else {
            // QR iteration
            for (;;) {
                int mq = lend;
                if (l != lend) {
                    for (mq = l; mq >= lend + 1; --mq) {
                        float tst = fm(E(mq - 1), E(mq - 1));
                        if (tst <= fa(fm(fm(eps2, fabsf(D(mq))), fabsf(D(mq - 1))), safmin)) break;
                    }
                }
                if (mq > lend) E(mq - 1) = 0.0f;
                float p = D(l);
                if (mq == l) { l -= 1; if (l >= lend) continue; break; }
                if (mq == l - 1) {
                    float rt1, rt2, cc, ss;
                    slaev2_(D(l - 1), E(l - 1), D(l), rt1, rt2, cc, ss);
                    rotcf(wk, l - 1, l, cc, ss);
                    D(l - 1) = rt1; D(l) = rt2; E(l - 1) = 0.0f;
                    l -= 2; if (l >= lend) continue; break;
                }
                if (jtot == nmaxit) break;
                jtot++;
                // form shift
                float g = fs(D(l - 1), p) / fm(2.0f, E(l - 1));
                float r = slapy2_(g, 1.0f);
                g = fa(fs(D(mq), p), E(l - 1) / fa(g, fsignf(r, g)));
                float s_ = 1.0f, c_ = 1.0f; p = 0.0f;
                for (int i = mq; i <= l - 1; ++i) {
                    float f = fm(s_, E(i)), b = fm(c_, E(i));
                    slartg_(g, f, c_, s_, r);
                    if (i != mq) E(i - 1) = r;
                    g = fs(D(i), p);
                    r = fa(fm(fs(D(i + 1), g), s_), fm(fm(2.0f, c_), b));
                    p = fm(s_, r);
                    D(i) = fa(g, p);
                    g = fs(fm(c_, r), b);
                    WC(i) = c_; WSN(i) = s_;      // QR stores +S
                }
                for (int i = mq; i <= l - 1; ++i) rotcf(wk, i, i + 1, WC(i), WSN(i));
                D(l) = fs(D(l), p); E(l - 1) = g;
            }
        }
    }
    // ascending selection sort with column swaps (ssteqr tail)
    for (int ii = 2; ii <= 3; ++ii) {
        int i = ii - 1, kk = i; float p = D(i);
        for (int j = ii; j <= 3; ++j) if (D(j) < p) { kk = j; p = D(j); }
        if (kk != i) {
            D(kk) = D(i); D(i) = p;
            for (int r = 1; r <= 3; ++r) { float t = Z(r, i); Z(r, i) = Z(r, kk); Z(r, kk) = t; }
        }
    }
    // sormtr: Z := H1 * Z (rows 2..3), slarf/sger op order
    if (tau != 0.0f) {
        for (int c = 1; c <= 3; ++c) {
            float ss = fa(Z(2, c), fm(v3, Z(3, c)));
            float t = fm(tau, ss);
            Z(2, c) = fs(Z(2, c), t);
            Z(3, c) = fs(Z(3, c), fm(t, v3));
        }
    }
    v1o = Z(1, 1); v2o = Z(2, 1); v3o = Z(3, 1);
}

// ---------------- JAX threefry2x32 (key(42) noise reproduction)
__device__ void threefry2x32_(unsigned k0, unsigned k1, unsigned c0, unsigned c1,
                              unsigned& o0, unsigned& o1) {
    const unsigned rot[8] = {13u, 15u, 26u, 6u, 17u, 29u, 16u, 24u};
    unsigned ks[3] = {k0, k1, k0 ^ k1 ^ 0x1BD11BDAu};
    unsigned x0 = c0 + k0, x1 = c1 + k1;
    for (int blk = 0; blk < 5; ++blk) {
        const unsigned* r = &rot[(blk & 1) * 4];
        for (int i = 0; i < 4; ++i) {
            x0 += x1;
            x1 = (x1 << r[i]) | (x1 >> (32 - r[i]));
            x1 ^= x0;
        }
        x0 += ks[(blk + 1) % 3];
        x1 += ks[(blk + 2) % 3] + (unsigned)(blk + 1);
    }
    o0 = x0; o1 = x1;
}

// noise[j] = (uniform(key(42),(100,3))[j,j] - 0.5) * 1e-8 ; flat idx m = 4*j
__device__ float noise_diag_(int j) {
    unsigned m = (unsigned)(4 * j);
    unsigned o0, o1;
    threefry2x32_(0u, 42u, m, 150u + m, o0, o1);  // m<150 -> first-half output
    unsigned bits = (o0 >> 9) | 0x3f800000u;
    float u = fs(__uint_as_float(bits), 1.0f);    // [0,1)
    return fm(fs(u, 0.5f), 1e-8f);
}

__device__ __forceinline__ float angf(float ax, float ay, float az,
                                      float bx, float by, float bz) {
    float cx = ay * bz - az * by;
    float cy = az * bx - ax * bz;
    float cz = ax * by - ay * bx;
    float cn = sqrtf(cx * cx + cy * cy + cz * cz);
    float d  = ax * bx + ay * by + az * bz;
    return atan2f(cn, d);
}

// ---------------------------------------------------------------- kernels

__global__ void k_prep(const float* __restrict__ pts, float4* __restrict__ pos4, int n) {
    int i = blockIdx.x * blockDim.x + threadIdx.x;
    if (i < n) {
        float x = pts[i * 3], y = pts[i * 3 + 1], z = pts[i * 3 + 2];
        float sq = fa(fa(fm(x, x), fm(y, y)), fm(z, z));
        pos4[i] = make_float4(x, y, z, sq);
    }
}

// Exact brute-force KNN, 12 smallest (d2 asc, idx asc ties). (unchanged R9)
#define KEY_WORST 0xC0001FFFFFFFFFFFull
#define CBUF 128

__global__ __launch_bounds__(256) void k_knn(const float4* __restrict__ pos4,
                                             int* __restrict__ cols, int n) {
    __shared__ unsigned long long sbuf[4][CBUF];
    __shared__ int scnt[4];
    __shared__ unsigned stq[4][4];

    int lane = threadIdx.x & 63;
    int wv = threadIdx.x >> 6;
    int ibase = blockIdx.x * 4;
    int nm1 = n - 1;

    if (threadIdx.x < 4) scnt[threadIdx.x] = 0;

    float4 P[4];
#pragma unroll
    for (int p = 0; p < 4; ++p) {
        int ipp = (ibase + p <= nm1) ? (ibase + p) : nm1;
        P[p] = pos4[ipp];
    }

    int qlen = (n + 3) >> 2;
    int jlo = wv * qlen;
    int jhi = jlo + qlen; if (jhi > n) jhi = n;

    // ---- pass 1: per-lane top-2 raw-bit d2 per point over this quarter
    unsigned b0[4], b1[4];
#pragma unroll
    for (int p = 0; p < 4; ++p) { b0[p] = 0xFFFFFFFFu; b1[p] = 0xFFFFFFFFu; }
    {
        int j0 = jlo + lane; j0 = (j0 <= nm1) ? j0 : nm1;
        float4 Qn = pos4[j0];
        for (int j = jlo + lane; j < jhi; j += 64) {
            float4 Q = Qn;
            int jn = j + 64; jn = (jn <= nm1) ? jn : nm1;
            Qn = pos4[jn];
#pragma unroll
            for (int p = 0; p < 4; ++p) {
                float g = fm(P[p].x, Q.x);
                g = fmaf(P[p].y, Q.y, g);
                g = fmaf(P[p].z, Q.z, g);
                float d2 = fs(fa(P[p].w, Q.w), fm(2.0f, g));
                unsigned u = __float_as_uint(d2);
                unsigned lo = umin32(b0[p], u);
                unsigned hi = umax32(b0[p], u);
                b0[p] = lo;
                b1[p] = umin32(b1[p], hi);
            }
        }
    }

    // ---- quarter-local 13th smallest captured -> stq[p][wv]
#pragma unroll
    for (int p = 0; p < 4; ++p) {
        unsigned h0 = b0[p], h1 = b1[p];
        unsigned T = 0xFFFFFFFFu;
        for (int r = 0; r < KNB + 1; ++r) {
            unsigned mn = h0;
#pragma unroll
            for (int off = 32; off >= 1; off >>= 1) {
                unsigned o = (unsigned)__shfl_xor((int)mn, off, 64);
                mn = umin32(mn, o);
            }
            unsigned long long bl = __ballot(h0 == mn);
            int first = __ffsll(bl) - 1;
            if (lane == first) { h0 = h1; h1 = 0xFFFFFFFFu; }
            T = mn;
        }
        if (lane == 0) stq[p][wv] = T;
    }
    __syncthreads();

    unsigned Tu[4];
#pragma unroll
    for (int p = 0; p < 4; ++p) {
        unsigned t0 = stq[p][0], t1 = stq[p][1], t2 = stq[p][2], t3 = stq[p][3];
        Tu[p] = umax32(umax32(t0, t1), umax32(t2, t3));
    }

    // ---- pass 2: compact candidates with bits <= Tu into shared buffer
    {
        int j0 = jlo + lane; j0 = (j0 <= nm1) ? j0 : nm1;
        float4 Qn = pos4[j0];
        for (int j = jlo + lane; j < jhi; j += 64) {
            float4 Q = Qn;
            int jn = j + 64; jn = (jn <= nm1) ? jn : nm1;
            Qn = pos4[jn];
#pragma unroll
            for (int p = 0; p < 4; ++p) {
                float g = fm(P[p].x, Q.x);
                g = fmaf(P[p].y, Q.y, g);
                g = fmaf(P[p].z, Q.z, g);
                float d2 = fs(fa(P[p].w, Q.w), fm(2.0f, g));
                unsigned u = __float_as_uint(d2);
                bool c = (u <= Tu[p]) && (j != ibase + p);
                unsigned long long bl = __ballot(c);
                if (bl) {
                    int leader = __ffsll(bl) - 1;
                    int base = 0;
                    if (lane == leader)
                        base = atomicAdd(&scnt[p], (int)__popcll(bl));
                    base = __shfl(base, leader, 64);
                    if (c) {
                        int pos = base + (int)__popcll(bl & ((1ull << lane) - 1ull));
                        unsigned us = u ^ (unsigned)(((int)u >> 31) | 0x80000000);
                        unsigned long long kb = (((unsigned long long)us << 13) | (unsigned)j)
                                                | 0xC000000000000000ull;
                        if (pos < CBUF) sbuf[p][pos] = kb;
                    }
                }
            }
        }
    }
    __syncthreads();

    // ---- final: wave wv finalizes point wv (reload from pos4; no runtime
    // indexing of register arrays -- avoids scratch, see R8 post-mortem)
    {
        int io = ibase + wv;
        if (io < n) {
            int cnt = scnt[wv];
            if (cnt > CBUF) {
                float4 Pp = pos4[io];
                unsigned lst[KNB];
#pragma unroll
                for (int k = 0; k < KNB; ++k) lst[k] = 0xFFFFFFFFu;
                for (int j = lane; j < n; j += 64) {
                    float4 Q = pos4[j];
                    float g = fm(Pp.x, Q.x);
                    g = fmaf(Pp.y, Q.y, g);
                    g = fmaf(Pp.z, Q.z, g);
                    float d2 = fs(fa(Pp.w, Q.w), fm(2.0f, g));
                    unsigned u = __float_as_uint(d2);
                    unsigned us = u ^ (unsigned)(((int)u >> 31) | 0x80000000);
                    if (j == io) us = 0xFFFFFFFFu;
#pragma unroll
                    for (int k = 0; k < KNB; ++k) {
                        unsigned lo = umin32(lst[k], us);
                        unsigned hi = umax32(lst[k], us);
                        lst[k] = lo; us = hi;
                    }
                }
                unsigned Ts = 0xFFFFFFFFu;
                for (int r = 0; r < KNB; ++r) {
                    unsigned mn = lst[0];
#pragma unroll
                    for (int off = 32; off >= 1; off >>= 1) {
                        unsigned o = (unsigned)__shfl_xor((int)mn, off, 64);
                        mn = umin32(mn, o);
                    }
                    unsigned long long bl2 = __ballot(lst[0] == mn);
                    int first = __ffsll(bl2) - 1;
                    if (lane == first) {
#pragma unroll
                        for (int k = 0; k < KNB - 1; ++k) lst[k] = lst[k + 1];
                        lst[KNB - 1] = 0xFFFFFFFFu;
                    }
                    Ts = mn;
                }
                if (lane == 0) scnt[wv] = 0;
                __builtin_amdgcn_wave_barrier();
                for (int j = lane; j < n; j += 64) {
                    float4 Q = pos4[j];
                    float g = fm(Pp.x, Q.x);
                    g = fmaf(Pp.y, Q.y, g);
                    g = fmaf(Pp.z, Q.z, g);
                    float d2 = fs(fa(Pp.w, Q.w), fm(2.0f, g));
                    unsigned u = __float_as_uint(d2);
                    unsigned us = u ^ (unsigned)(((int)u >> 31) | 0x80000000);
                    bool c = (us <= Ts) && (j != io);
                    unsigned long long bl2 = __ballot(c);
                    if (bl2) {
                        int leader = __ffsll(bl2) - 1;
                        int base = 0;
                        if (lane == leader)
                            base = atomicAdd(&scnt[wv], (int)__popcll(bl2));
                        base = __shfl(base, leader, 64);
                        if (c) {
                            int pos = base + (int)__popcll(bl2 & ((1ull << lane) - 1ull));
                            unsigned long long kb = (((unsigned long long)us << 13) | (unsigned)j)
                                                    | 0xC000000000000000ull;
                            if (pos < CBUF) sbuf[wv][pos] = kb;
                        }
                    }
                }
                cnt = scnt[wv];
                if (cnt > CBUF) cnt = CBUF;
            }

            double k0 = __longlong_as_double((long long)KEY_WORST);
            double k1 = __longlong_as_double((long long)KEY_WORST);
            if (lane < cnt) k0 = __longlong_as_double((long long)sbuf[wv][lane]);
            if (lane + 64 < cnt) k1 = __longlong_as_double((long long)sbuf[wv][lane + 64]);
            double mykey = __longlong_as_double((long long)KEY_WORST);
            for (int r = 0; r < KNB; ++r) {
                double mx = fmax(k0, k1);
#pragma unroll
                for (int off = 32; off >= 1; off >>= 1)
                    mx = fmax(mx, __shfl_xor(mx, off, 64));
                if (k0 == mx) k0 = __longlong_as_double((long long)KEY_WORST);
                else if (k1 == mx) k1 = __longlong_as_double((long long)KEY_WORST);
                if (lane == r) mykey = mx;
            }
            if (lane < KNB) {
                unsigned long long bits = (unsigned long long)__double_as_longlong(mykey);
                unsigned j = (unsigned)(bits & 0x1FFFu);
                unsigned u = (unsigned)((bits >> 13) & 0xFFFFFFFFull);
                unsigned ob = (u & 0x80000000u) ? (u ^ 0x80000000u) : ~u;
                float d2 = __uint_as_float(ob);
                cols[io * KNB + lane] = (d2 <= 0.25f) ? (int)j : io;
            }
        }
    }
}

// Per-thread eig workspace in LDS (stride 19: odd -> lanes spread banks).
__global__ __launch_bounds__(64) void k_normals(const float4* __restrict__ pos4,
                                                const int* __restrict__ cols,
                                                float4* __restrict__ nrm4,
                                                float* __restrict__ out, int n) {
    __shared__ float swk[64][19];
    int i = blockIdx.x * blockDim.x + threadIdx.x;
    if (i >= n) return;
    float* wk = swk[threadIdx.x];

    float qx[KNB], qy[KNB], qz[KNB];
#pragma unroll
    for (int k = 0; k < KNB; ++k) {
        float4 q = pos4[cols[i * KNB + k]];
        qx[k] = q.x; qy[k] = q.y; qz[k] = q.z;
    }
    // mean: f32 sequential over k
    float sx = qx[0], sy = qy[0], sz = qz[0];
#pragma unroll
    for (int k = 1; k < KNB; ++k) { sx = fa(sx, qx[k]); sy = fa(sy, qy[k]); sz = fa(sz, qz[k]); }
    float mx = sx / 12.0f, my = sy / 12.0f, mz = sz / 12.0f;
    // cov: f32 sequential over k (np.einsum order)
    float c00 = 0, c10 = 0, c20 = 0, c11 = 0, c21 = 0, c22 = 0;
#pragma unroll
    for (int k = 0; k < KNB; ++k) {
        float dx = fs(qx[k], mx), dy = fs(qy[k], my), dz = fs(qz[k], mz);
        c00 = fa(c00, fm(dx, dx));
        c10 = fa(c10, fm(dy, dx));
        c20 = fa(c20, fm(dz, dx));
        c11 = fa(c11, fm(dy, dy));
        c21 = fa(c21, fm(dz, dy));
        c22 = fa(c22, fm(dz, dz));
    }
    c00 = c00 / 12.0f; c10 = c10 / 12.0f; c20 = c20 / 12.0f;
    c11 = c11 / 12.0f; c21 = c21 / 12.0f; c22 = c22 / 12.0f;
    // + jnp.diag(noise): np eigh reads lower, A[i][j] += v[j]
    float v0 = noise_diag_(0), v1 = noise_diag_(1), v2 = noise_diag_(2);
    float a00 = fa(c00, v0), a10 = fa(c10, v0), a20 = fa(c20, v0);
    float a11 = fa(c11, v1), a21 = fa(c21, v1), a22 = fa(c22, v2);
    float e1, e2, e3;
    eig3_smallest_f32(wk, a00, a10, a20, a11, a21, a22, e1, e2, e3);
    nrm4[i] = make_float4(e1, e2, e3, 0.0f);
    out[i]         = e1;
    out[n + i]     = e2;
    out[2 * n + i] = e3;
}

// ---------------------------------------------------------------- MLP chain
// Weights read directly from global (wave-uniform -> SMEM/scalar cache).

struct WPtrs { const float* p[28]; };

template <int NI, int NH, int NO>
__device__ void mlpg(const float* __restrict__ w1, const float* __restrict__ b1,
                     const float* __restrict__ w2, const float* __restrict__ b2,
                     const float* in, float* out) {
#pragma unroll
    for (int o = 0; o < NO; ++o) out[o] = b2[o];
    for (int h = 0; h < NH; ++h) {
        float hh = b1[h];
#pragma unroll
        for (int ii = 0; ii < NI; ++ii) hh = fmaf(in[ii], w1[ii * NH + h], hh);
        hh = fmaxf(hh, 0.0f);
#pragma unroll
        for (int o = 0; o < NO; ++o) out[o] = fmaf(hh, w2[h * NO + o], out[o]);
    }
}

__global__ __launch_bounds__(192) void k_mlp(const float4* __restrict__ pos4,
                                             const int* __restrict__ cols,
                                             const float4* __restrict__ nrm4,
                                             WPtrs wp, float* __restrict__ out, int n) {
    __shared__ float sx[16 * 12 * 16];
    __shared__ float sg[16 * 12];
    __shared__ float smat[16 * 9];
    __shared__ float sfeat[16 * 8];
    __shared__ float slog[16 * 12];
    __shared__ float sred[16 * 2];

    int p = threadIdx.x / 12, k = threadIdx.x - p * 12;
    int nn = blockIdx.x * 16 + p;
    bool act = (nn < n);

    float cx = 0, cy = 0, cz = 0, nrx = 0, nry = 0, nrz = 0;
    float xr[16];

    // stage A: edge features + l1
    if (act) {
        int col = cols[nn * 12 + k];
        float4 P = pos4[nn], Q = pos4[col];
        cx = Q.x - P.x; cy = Q.y - P.y; cz = Q.z - P.z;
        float dist = sqrtf(cx * cx + cy * cy + cz * cz);
        float4 NR = nrm4[nn], NC = nrm4[col];
        nrx = NR.x; nry = NR.y; nrz = NR.z;
        float a1 = angf(nrx, nry, nrz, cx, cy, cz);
        float a2 = angf(NC.x, NC.y, NC.z, cx, cy, cz);
        float a3 = angf(nrx, nry, nrz, NC.x, NC.y, NC.z);
        float in7[7] = {cx, cy, cz, dist, a1, a2, a3};
        mlpg<7, 32, 16>(wp.p[0], wp.p[1], wp.p[2], wp.p[3], in7, xr);
#pragma unroll
        for (int o = 0; o < 16; ++o) sx[(p * 12 + k) * 16 + o] = xr[o];
    }
    __syncthreads();

    // stage B: g1
    if (act && k == 0) {
        float in19[19];
#pragma unroll
        for (int o = 0; o < 16; ++o) {
            float s = 0;
            for (int kk = 0; kk < 12; ++kk) s += sx[(p * 12 + kk) * 16 + o];
            in19[o] = s / 12.0f;
        }
        in19[16] = nrx; in19[17] = nry; in19[18] = nrz;
        float og[8];
        mlpg<19, 32, 8>(wp.p[4], wp.p[5], wp.p[6], wp.p[7], in19, og);
#pragma unroll
        for (int o = 0; o < 8; ++o) sg[p * 12 + o] = og[o];
    }
    __syncthreads();

    // stage C: l2
    if (act) {
        float in24[24];
#pragma unroll
        for (int o = 0; o < 16; ++o) in24[o] = xr[o];
#pragma unroll
        for (int o = 0; o < 8; ++o) in24[16 + o] = sg[p * 12 + o];
        mlpg<24, 32, 16>(wp.p[8], wp.p[9], wp.p[10], wp.p[11], in24, xr);
#pragma unroll
        for (int o = 0; o < 16; ++o) sx[(p * 12 + k) * 16 + o] = xr[o];
    }
    __syncthreads();

    // stage D: g2
    if (act && k == 0) {
        float in16[16];
#pragma unroll
        for (int o = 0; o < 16; ++o) {
            float s = 0;
            for (int kk = 0; kk < 12; ++kk) s += sx[(p * 12 + kk) * 16 + o];
            in16[o] = s / 12.0f;
        }
        float og[8];
        mlpg<16, 32, 8>(wp.p[12], wp.p[13], wp.p[14], wp.p[15], in16, og);
#pragma unroll
        for (int o = 0; o < 8; ++o) sg[p * 12 + o] = og[o];
    }
    __syncthreads();

    // stage E: l3
    if (act) {
        float in24[24];
#pragma unroll
        for (int o = 0; o < 16; ++o) in24[o] = xr[o];
#pragma unroll
        for (int o = 0; o < 8; ++o) in24[16 + o] = sg[p * 12 + o];
        mlpg<24, 32, 16>(wp.p[16], wp.p[17], wp.p[18], wp.p[19], in24, xr);
#pragma unroll
        for (int o = 0; o < 16; ++o) sx[(p * 12 + k) * 16 + o] = xr[o];
    }
    __syncthreads();

    // stage F: g3 + quat -> rot matrix
    if (act && k == 0) {
        float in16[16];
#pragma unroll
        for (int o = 0; o < 16; ++o) {
            float s = 0;
            for (int kk = 0; kk < 12; ++kk) s += sx[(p * 12 + kk) * 16 + o];
            in16[o] = s / 12.0f;
        }
        float og[12];
        mlpg<16, 32, 12>(wp.p[20], wp.p[21], wp.p[22], wp.p[23], in16, og);
        float q0 = og[0], q1 = og[1], q2 = og[2], q3 = og[3];
        float qn = sqrtf(q0 * q0 + q1 * q1 + q2 * q2 + q3 * q3) + 1e-8f;
        q0 /= qn; q1 /= qn; q2 /= qn; q3 /= qn;
        float qw = q0, qx = q1, qy = q2, qz = q3;
        smat[p * 9 + 0] = 1.0f - 2.0f * (qy * qy + qz * qz);
        smat[p * 9 + 1] = 2.0f * (qx * qy - qz * qw);
        smat[p * 9 + 2] = 2.0f * (qx * qz + qy * qw);
        smat[p * 9 + 3] = 2.0f * (qx * qy + qz * qw);
        smat[p * 9 + 4] = 1.0f - 2.0f * (qx * qx + qz * qz);
        smat[p * 9 + 5] = 2.0f * (qy * qz - qx * qw);
        smat[p * 9 + 6] = 2.0f * (qx * qz - qy * qw);
        smat[p * 9 + 7] = 2.0f * (qy * qz + qx * qw);
        smat[p * 9 + 8] = 1.0f - 2.0f * (qx * qx + qy * qy);
#pragma unroll
        for (int o = 0; o < 8; ++o) sfeat[p * 8 + o] = og[4 + o];
    }
    __syncthreads();

    // stage G: l4 logits
    if (act) {
        float r0 = smat[p * 9 + 0] * cx + smat[p * 9 + 1] * cy + smat[p * 9 + 2] * cz;
        float r1 = smat[p * 9 + 3] * cx + smat[p * 9 + 4] * cy + smat[p * 9 + 5] * cz;
        float r2 = smat[p * 9 + 6] * cx + smat[p * 9 + 7] * cy + smat[p * 9 + 8] * cz;
        float in27[27];
#pragma unroll
        for (int o = 0; o < 16; ++o) in27[o] = xr[o];
#pragma unroll
        for (int o = 0; o < 8; ++o) in27[16 + o] = sfeat[p * 8 + o];
        in27[24] = r0; in27[25] = r1; in27[26] = r2;
        float lg[1];
        mlpg<27, 64, 1>(wp.p[24], wp.p[25], wp.p[26], wp.p[27], in27, lg);
        slog[p * 12 + k] = lg[0];
    }
    __syncthreads();

    // stage H: softmax over the 12 edges
    if (act && k == 0) {
        float mx = slog[p * 12];
        for (int kk = 1; kk < 12; ++kk) mx = fmaxf(mx, slog[p * 12 + kk]);
        float se = 0;
        for (int kk = 0; kk < 12; ++kk) se += expf(slog[p * 12 + kk] - mx);
        sred[p * 2] = mx; sred[p * 2 + 1] = se;
    }
    __syncthreads();
    if (act) {
        float v = expf(slog[p * 12 + k] - sred[p * 2]) / sred[p * 2 + 1];
        out[3 * n + k * n + nn] = v;
    }
}

// ---------------------------------------------------------------- launch

extern "C" void kernel_launch(void* const* d_in, const int* in_sizes, int n_in,
                              void* d_out, int out_size, void* d_ws, size_t ws_size,
                              hipStream_t stream) {
    const float* pts = (const float*)d_in[0];
    int n = in_sizes[0] / 3;

    float4* pos4 = (float4*)d_ws;
    int*    cols = (int*)((char*)d_ws + (size_t)n * 16);
    float4* nrm4 = (float4*)((char*)d_ws + (size_t)n * 16 + (size_t)n * KNB * 4);
    float*  out  = (float*)d_out;

    WPtrs wp;
    for (int a = 0; a < 28; ++a) wp.p[a] = (const float*)d_in[a + 1];

    k_prep<<<(n + 255) / 256, 256, 0, stream>>>(pts, pos4, n);
    // 4 points per block; 4 waves split the candidate range (j) in quarters
    k_knn<<<(n + 3) / 4, 256, 0, stream>>>(pos4, cols, n);
    // block=64, LDS workspace: eig's dynamically-indexed arrays live in LDS
    k_normals<<<(n + 63) / 64, 64, 0, stream>>>(pos4, cols, nrm4, out, n);
    k_mlp<<<(n + 15) / 16, 192, 0, stream>>>(pos4, cols, nrm4, wp, out, n);
}